// Round 2
// baseline (324.843 us; speedup 1.0000x reference)
//
#include <hip/hip_runtime.h>

// MultiHeadSelfAttention (faithful-bug version): qkv = x@Wqkv^T; attention over
// FULL 1024-dim "head"; scale 1/sqrt(64); probs@v; scramble reshape; proj + bias.
// B=4, S=2048, E=1024, H=1024, 3H=3072.
//
// Pipeline (all bf16 MFMA, f32 accumulate):
//  1) convert x, w_qkv, w_proj to bf16 in ws
//  2) qkv = x @ w_qkv^T           (NT GEMM, bf16 out)
//  3) vT[b][h][k] = v[b][k][h]    (tiled transpose so PV is also NT)
//  4) per batch: scores = q@k^T (f32) -> softmax(*0.125) -> probs bf16
//  5) out2 = probs @ vT^T, stored SCRAMBLED: out2[b][2h+(q>>10)][q&1023]
//  6) out = out2 @ w_proj^T + b_proj  (f32 to d_out)

typedef float f32x4 __attribute__((ext_vector_type(4)));
typedef short bf16x8 __attribute__((ext_vector_type(8)));
typedef short bf16x4 __attribute__((ext_vector_type(4)));
typedef unsigned short u16;

#define BM 128
#define BN 128
#define BK 32

__device__ inline u16 f2bf(float f) {  // round-to-nearest-even f32 -> bf16 bits
  union { float f; unsigned u; } x; x.f = f;
  unsigned r = x.u + 0x7fffu + ((x.u >> 16) & 1u);
  return (u16)(r >> 16);
}

__device__ inline void gload_lds16(const void* g, void* l) {
  __builtin_amdgcn_global_load_lds(
      (const __attribute__((address_space(1))) void*)g,
      (__attribute__((address_space(3))) void*)l, 16, 0, 0);
}

// ---------------- f32 -> bf16 conversion (memory-bound) ----------------
__global__ __launch_bounds__(256) void cvt_kernel(const float* __restrict__ in,
                                                  u16* __restrict__ out, int n8) {
  int i = blockIdx.x * 256 + threadIdx.x;
  if (i >= n8) return;
  f32x4 a = *(const f32x4*)&in[(long)i * 8];
  f32x4 b = *(const f32x4*)&in[(long)i * 8 + 4];
  bf16x8 o;
#pragma unroll
  for (int j = 0; j < 4; ++j) { o[j] = (short)f2bf(a[j]); o[4 + j] = (short)f2bf(b[j]); }
  *(bf16x8*)&out[(long)i * 8] = o;
}

// ---------------- V transpose: vT[b][h][k] = qkv[b][k][2048+h] ----------------
__global__ __launch_bounds__(256) void transpose_v(const u16* __restrict__ qkvb,
                                                   u16* __restrict__ vT) {
  __shared__ u16 tile[64][72];
  const int t = threadIdx.x;
  const long b = blockIdx.z;
  const int k0 = blockIdx.x * 64, h0 = blockIdx.y * 64;
  const u16* v = qkvb + b * 2048 * 3072 + 2048;
#pragma unroll
  for (int i = 0; i < 2; ++i) {
    int s = i * 256 + t; int r = s >> 3, c = (s & 7) * 8;
    bf16x8 val = *(const bf16x8*)&v[(long)(k0 + r) * 3072 + h0 + c];
    *(bf16x8*)&tile[r][c] = val;
  }
  __syncthreads();
  u16* o = vT + b * 1024 * 2048;
#pragma unroll
  for (int i = 0; i < 2; ++i) {
    int s = i * 256 + t; int r = s >> 3, c = (s & 7) * 8;
    bf16x8 val;
#pragma unroll
    for (int j = 0; j < 8; ++j) val[j] = tile[c + j][r];
    *(bf16x8*)&o[(long)(h0 + r) * 2048 + k0 + c] = val;
  }
}

// ---------------- row softmax: probs = softmax(scores * 0.125), bf16 out ------
__global__ __launch_bounds__(256) void softmax_k(const float* __restrict__ S,
                                                 u16* __restrict__ P,
                                                 long sS, long sP) {
  const int t = threadIdx.x;
  const float* row = S + (long)blockIdx.z * sS + (long)blockIdx.x * 2048;
  u16* prow = P + (long)blockIdx.z * sP + (long)blockIdx.x * 2048;
  f32x4 v0 = *(const f32x4*)&row[t * 8];
  f32x4 v1 = *(const f32x4*)&row[t * 8 + 4];
  float m = v0[0];
#pragma unroll
  for (int j = 1; j < 4; ++j) m = fmaxf(m, v0[j]);
#pragma unroll
  for (int j = 0; j < 4; ++j) m = fmaxf(m, v1[j]);
#pragma unroll
  for (int o = 32; o; o >>= 1) m = fmaxf(m, __shfl_xor(m, o));
  __shared__ float red[8];
  if ((t & 63) == 0) red[t >> 6] = m;
  __syncthreads();
  m = fmaxf(fmaxf(red[0], red[1]), fmaxf(red[2], red[3]));
  const float C = 0.18033688011112042f;  // 0.125 * log2(e)
  float e[8], s = 0.f;
#pragma unroll
  for (int j = 0; j < 4; ++j) { e[j] = exp2f((v0[j] - m) * C); s += e[j]; }
#pragma unroll
  for (int j = 0; j < 4; ++j) { e[4 + j] = exp2f((v1[j] - m) * C); s += e[4 + j]; }
#pragma unroll
  for (int o = 32; o; o >>= 1) s += __shfl_xor(s, o);
  if ((t & 63) == 0) red[4 + (t >> 6)] = s;
  __syncthreads();
  float inv = 1.f / (red[4] + red[5] + red[6] + red[7]);
  bf16x8 ov;
#pragma unroll
  for (int j = 0; j < 8; ++j) ov[j] = (short)f2bf(e[j] * inv);
  *(bf16x8*)&prow[t * 8] = ov;
}

// ---------------- NT GEMM: C[m][n] = sum_k A[m][k]*B[n][k] --------------------
// MODE 0: f32 store | 1: bf16 store | 2: bf16 scramble store (PV) | 3: f32+bias
template <int MODE>
__global__ __launch_bounds__(256) void gemm_nt(const u16* __restrict__ A0, int lda, long sAz,
                                               const u16* __restrict__ B0, int ldb, long sBz,
                                               void* __restrict__ C0, int ldc, long sCz,
                                               const float* __restrict__ bias, int K) {
  __shared__ u16 As[2][BM * BK];
  __shared__ u16 Bs[2][BM * BK];
  const int t = threadIdx.x;
  const int lane = t & 63, wv = t >> 6;
  const long row0 = (long)blockIdx.y * BM, col0 = (long)blockIdx.x * BN;
  const u16* A = A0 + (long)blockIdx.z * sAz;
  const u16* B = B0 + (long)blockIdx.z * sBz;

  f32x4 acc[4][4];
#pragma unroll
  for (int m = 0; m < 4; ++m)
#pragma unroll
    for (int n = 0; n < 4; ++n) acc[m][n] = (f32x4){0.f, 0.f, 0.f, 0.f};

  const int wrow = (wv >> 1) * 64, wcol = (wv & 1) * 64;
  const int fr = lane & 15, fk = (lane >> 4) * 8;

  auto stage = [&](int buf, int k0) {
#pragma unroll
    for (int i = 0; i < 2; ++i) {
      int c = i * 256 + wv * 64 + lane;
      int r = c >> 2, sl = c & 3;
      gload_lds16(A + (row0 + r) * lda + k0 + sl * 8, &As[buf][(i * 256 + wv * 64) * 8]);
    }
#pragma unroll
    for (int i = 0; i < 2; ++i) {
      int c = i * 256 + wv * 64 + lane;
      int r = c >> 2, sl = c & 3;
      gload_lds16(B + (col0 + r) * ldb + k0 + sl * 8, &Bs[buf][(i * 256 + wv * 64) * 8]);
    }
  };

  stage(0, 0);
  __syncthreads();
  const int NK = K / BK;
  for (int kt = 0; kt < NK; ++kt) {
    const int cur = kt & 1;
    if (kt + 1 < NK) stage(cur ^ 1, (kt + 1) * BK);
    bf16x8 af[4], bf[4];
#pragma unroll
    for (int m = 0; m < 4; ++m)
      af[m] = *(const bf16x8*)&As[cur][(wrow + m * 16 + fr) * BK + fk];
#pragma unroll
    for (int n = 0; n < 4; ++n)
      bf[n] = *(const bf16x8*)&Bs[cur][(wcol + n * 16 + fr) * BK + fk];
#pragma unroll
    for (int m = 0; m < 4; ++m)
#pragma unroll
      for (int n = 0; n < 4; ++n)
        acc[m][n] = __builtin_amdgcn_mfma_f32_16x16x32_bf16(af[m], bf[n], acc[m][n], 0, 0, 0);
    __syncthreads();  // drains vmcnt (stage done) + all reads of cur finished
  }

  const int fq = lane >> 4;
#pragma unroll
  for (int m = 0; m < 4; ++m)
#pragma unroll
    for (int n = 0; n < 4; ++n) {
      const long r0 = row0 + wrow + m * 16 + fq * 4;
      const long c = col0 + wcol + n * 16 + fr;
      if (MODE == 0) {
        float* C = (float*)C0 + (long)blockIdx.z * sCz;
#pragma unroll
        for (int j = 0; j < 4; ++j) C[(r0 + j) * ldc + c] = acc[m][n][j];
      } else if (MODE == 1) {
        u16* C = (u16*)C0 + (long)blockIdx.z * sCz;
#pragma unroll
        for (int j = 0; j < 4; ++j) C[(r0 + j) * ldc + c] = f2bf(acc[m][n][j]);
      } else if (MODE == 2) {
        // C index space: m-dim = q (0..2047 within batch), n-dim = h.
        // scramble: out2[2h + (q>>10)][q & 1023]
        u16* C = (u16*)C0 + (long)blockIdx.z * sCz;
        const int q0 = (int)r0;
        const long dr = 2 * c + (q0 >> 10);
        bf16x4 pk;
#pragma unroll
        for (int j = 0; j < 4; ++j) pk[j] = (short)f2bf(acc[m][n][j]);
        *(bf16x4*)&C[dr * 1024 + (q0 & 1023)] = pk;
      } else {
        float* C = (float*)C0 + (long)blockIdx.z * sCz;
        const float bv = bias[c];
#pragma unroll
        for (int j = 0; j < 4; ++j) C[(r0 + j) * ldc + c] = acc[m][n][j] + bv;
      }
    }
}

// ---------------- launch ----------------
extern "C" void kernel_launch(void* const* d_in, const int* in_sizes, int n_in,
                              void* d_out, int out_size, void* d_ws, size_t ws_size,
                              hipStream_t stream) {
  const float* x      = (const float*)d_in[0];  // [4,2048,1024]
  const float* w_qkv  = (const float*)d_in[1];  // [3072,1024]
  const float* w_proj = (const float*)d_in[2];  // [1024,1024]
  const float* b_proj = (const float*)d_in[3];  // [1024]
  float* out = (float*)d_out;                   // [4,2048,1024]
  char* ws = (char*)d_ws;

  // ws layout (bytes)
  u16*   xb     = (u16*)(ws + 0);          // 16 MB
  u16*   wqkvb  = (u16*)(ws + 16777216);   //  6 MB
  u16*   wprojb = (u16*)(ws + 23068672);   //  2 MB
  u16*   qkvb   = (u16*)(ws + 25165824);   // 48 MB  [8192][3072]
  u16*   vT     = (u16*)(ws + 75497472);   // 16 MB  [4][1024][2048]
  u16*   out2   = (u16*)(ws + 92274688);   // 16 MB  [8192][1024] scrambled
  float* scores = (float*)(ws + 109051904);
  const bool full = ws_size >= 209715200ull;  // batched attention buffers fit?
  u16* probs = (u16*)(ws + (full ? 176160768 : 125829120));

  // 1) f32 -> bf16
  cvt_kernel<<<4096, 256, 0, stream>>>(x, xb, 1048576);
  cvt_kernel<<<1536, 256, 0, stream>>>(w_qkv, wqkvb, 393216);
  cvt_kernel<<<512, 256, 0, stream>>>(w_proj, wprojb, 131072);

  // 2) qkv = x @ w_qkv^T  (M=8192, N=3072, K=1024) -> bf16
  gemm_nt<1><<<dim3(24, 64, 1), 256, 0, stream>>>(xb, 1024, 0, wqkvb, 1024, 0,
                                                  qkvb, 3072, 0, nullptr, 1024);
  // 3) vT
  transpose_v<<<dim3(32, 16, 4), 256, 0, stream>>>(qkvb, vT);

  const long sQ = 2048L * 3072;
  if (full) {
    // 4) scores = q @ k^T (f32), all batches
    gemm_nt<0><<<dim3(16, 16, 4), 256, 0, stream>>>(qkvb, 3072, sQ, qkvb + 1024, 3072, sQ,
                                                    scores, 2048, 2048L * 2048, nullptr, 1024);
    softmax_k<<<dim3(2048, 1, 4), 256, 0, stream>>>(scores, probs, 2048L * 2048, 2048L * 2048);
    // 5) out2 = probs @ vT^T (M=2048 q, N=1024 h, K=2048), scramble store
    gemm_nt<2><<<dim3(8, 16, 4), 256, 0, stream>>>(probs, 2048, 2048L * 2048, vT, 2048, 2048L * 1024,
                                                   out2, 1024, 2048L * 1024, nullptr, 2048);
  } else {
    for (int b = 0; b < 4; ++b) {
      const u16* qb = qkvb + (long)b * sQ;
      gemm_nt<0><<<dim3(16, 16, 1), 256, 0, stream>>>(qb, 3072, 0, qb + 1024, 3072, 0,
                                                      scores, 2048, 0, nullptr, 1024);
      softmax_k<<<dim3(2048, 1, 1), 256, 0, stream>>>(scores, probs, 0, 0);
      gemm_nt<2><<<dim3(8, 16, 1), 256, 0, stream>>>(probs, 2048, 0, vT + (long)b * 2048 * 1024, 2048, 0,
                                                     out2 + (long)b * 2048 * 1024, 1024, 0, nullptr, 2048);
    }
  }

  // 6) out = out2 @ w_proj^T + b_proj (M=8192, N=1024, K=1024) -> f32 d_out
  gemm_nt<3><<<dim3(8, 64, 1), 256, 0, stream>>>(out2, 1024, 0, wprojb, 1024, 0,
                                                 out, 1024, 0, b_proj, 1024);
}

// Round 3
// 299.225 us; speedup vs baseline: 1.0856x; 1.0856x over previous
//
#include <hip/hip_runtime.h>

// MultiHeadSelfAttention (faithful-bug version): qkv = x@Wqkv^T; attention over
// FULL 1024-dim "head"; scale 1/sqrt(64); probs@v; scramble reshape; proj + bias.
// B=4, S=2048, E=1024, H=1024, 3H=3072.
//
// GEMMs use an 8-wave deep-pipelined NT template (T3+T4+T5 per guide §5.5):
//  - 512 threads (2M x 4N waves), BN=256, BM=256 or 128, BK=64 as 2x32 halves
//  - 64B LDS rows -> conflict-free ds_read_b128 frags, linear global_load_lds
//  - counted s_waitcnt vmcnt(N) at the 2 per-tile barriers (never 0 in loop)

typedef float f32x4 __attribute__((ext_vector_type(4)));
typedef short bf16x8 __attribute__((ext_vector_type(8)));
typedef short bf16x4 __attribute__((ext_vector_type(4)));
typedef unsigned short u16;

__device__ inline u16 f2bf(float f) {  // round-to-nearest-even f32 -> bf16 bits
  union { float f; unsigned u; } x; x.f = f;
  unsigned r = x.u + 0x7fffu + ((x.u >> 16) & 1u);
  return (u16)(r >> 16);
}

__device__ inline void gload_lds16(const void* g, void* l) {
  __builtin_amdgcn_global_load_lds(
      (const __attribute__((address_space(1))) void*)g,
      (__attribute__((address_space(3))) void*)l, 16, 0, 0);
}

// ---------------- f32 -> bf16 conversion (memory-bound) ----------------
__global__ __launch_bounds__(256) void cvt_kernel(const float* __restrict__ in,
                                                  u16* __restrict__ out, int n8) {
  int i = blockIdx.x * 256 + threadIdx.x;
  if (i >= n8) return;
  f32x4 a = *(const f32x4*)&in[(long)i * 8];
  f32x4 b = *(const f32x4*)&in[(long)i * 8 + 4];
  bf16x8 o;
#pragma unroll
  for (int j = 0; j < 4; ++j) { o[j] = (short)f2bf(a[j]); o[4 + j] = (short)f2bf(b[j]); }
  *(bf16x8*)&out[(long)i * 8] = o;
}

// ---------------- V transpose: vT[b][h][k] = qkv[b][k][2048+h] ----------------
__global__ __launch_bounds__(256) void transpose_v(const u16* __restrict__ qkvb,
                                                   u16* __restrict__ vT) {
  __shared__ u16 tile[64][72];
  const int t = threadIdx.x;
  const long b = blockIdx.z;
  const int k0 = blockIdx.x * 64, h0 = blockIdx.y * 64;
  const u16* v = qkvb + b * 2048 * 3072 + 2048;
#pragma unroll
  for (int i = 0; i < 2; ++i) {
    int s = i * 256 + t; int r = s >> 3, c = (s & 7) * 8;
    bf16x8 val = *(const bf16x8*)&v[(long)(k0 + r) * 3072 + h0 + c];
    *(bf16x8*)&tile[r][c] = val;
  }
  __syncthreads();
  u16* o = vT + b * 1024 * 2048;
#pragma unroll
  for (int i = 0; i < 2; ++i) {
    int s = i * 256 + t; int r = s >> 3, c = (s & 7) * 8;
    bf16x8 val;
#pragma unroll
    for (int j = 0; j < 8; ++j) val[j] = tile[c + j][r];
    *(bf16x8*)&o[(long)(h0 + r) * 2048 + k0 + c] = val;
  }
}

// ---------------- row softmax: probs = softmax(scores * 0.125), bf16 out ------
__global__ __launch_bounds__(256) void softmax_k(const float* __restrict__ S,
                                                 u16* __restrict__ P,
                                                 long sS, long sP) {
  const int t = threadIdx.x;
  const float* row = S + (long)blockIdx.z * sS + (long)blockIdx.x * 2048;
  u16* prow = P + (long)blockIdx.z * sP + (long)blockIdx.x * 2048;
  f32x4 v0 = *(const f32x4*)&row[t * 8];
  f32x4 v1 = *(const f32x4*)&row[t * 8 + 4];
  float m = v0[0];
#pragma unroll
  for (int j = 1; j < 4; ++j) m = fmaxf(m, v0[j]);
#pragma unroll
  for (int j = 0; j < 4; ++j) m = fmaxf(m, v1[j]);
#pragma unroll
  for (int o = 32; o; o >>= 1) m = fmaxf(m, __shfl_xor(m, o));
  __shared__ float red[8];
  if ((t & 63) == 0) red[t >> 6] = m;
  __syncthreads();
  m = fmaxf(fmaxf(red[0], red[1]), fmaxf(red[2], red[3]));
  const float C = 0.18033688011112042f;  // 0.125 * log2(e)
  float e[8], s = 0.f;
#pragma unroll
  for (int j = 0; j < 4; ++j) { e[j] = exp2f((v0[j] - m) * C); s += e[j]; }
#pragma unroll
  for (int j = 0; j < 4; ++j) { e[4 + j] = exp2f((v1[j] - m) * C); s += e[4 + j]; }
#pragma unroll
  for (int o = 32; o; o >>= 1) s += __shfl_xor(s, o);
  if ((t & 63) == 0) red[4 + (t >> 6)] = s;
  __syncthreads();
  float inv = 1.f / (red[4] + red[5] + red[6] + red[7]);
  bf16x8 ov;
#pragma unroll
  for (int j = 0; j < 8; ++j) ov[j] = (short)f2bf(e[j] * inv);
  *(bf16x8*)&prow[t * 8] = ov;
}

// ======== deep-pipelined NT GEMM: C[m][n] = sum_k A[m][k]*B[n][k] =============
// 512 threads = 8 waves (2M x 4N). BN=256 fixed; BMT = 256 or 128.
// LDS: A[2buf][2ks][BMT][32] + B[2buf][2ks][256][32] bf16 (rows=64B, conflict-free).
// Per K-tile (BK=64): 4 phases; stages for tile t+1 issue one chunk per phase;
// two barriers per tile with counted vmcnt(LA+2).
// MODE 0: f32 store | 1: bf16 store | 2: bf16 scramble store (PV) | 3: f32+bias
template <int MODE, int BMT>
__global__ __launch_bounds__(512, 2) void gemm8(const u16* __restrict__ A0, int lda, long sAz,
                                                const u16* __restrict__ B0, int ldb, long sBz,
                                                void* __restrict__ C0, int ldc, long sCz,
                                                const float* __restrict__ bias, int K) {
  constexpr int MF = BMT / 32;   // A frags per wave (8 or 4)
  constexpr int LA = BMT / 128;  // A stage loads per thread per ks-half (2 or 1)
  extern __shared__ __align__(16) u16 smem[];
  u16* Ab = smem;                      // [2*2][BMT][32]
  u16* Bb = smem + 4 * BMT * 32;       // [2*2][256][32]
  const int t = threadIdx.x, lane = t & 63, wv = t >> 6;
  const int wr = wv >> 2, wc = wv & 3;
  const int fr = lane & 15, hi = lane >> 4;
  const long row0 = (long)blockIdx.y * BMT, col0 = (long)blockIdx.x * 256;
  const u16* A = A0 + (long)blockIdx.z * sAz;
  const u16* B = B0 + (long)blockIdx.z * sBz;

  f32x4 acc[MF][4];
#pragma unroll
  for (int m = 0; m < MF; ++m)
#pragma unroll
    for (int n = 0; n < 4; ++n) acc[m][n] = (f32x4){0.f, 0.f, 0.f, 0.f};

  auto stageA = [&](int buf, int ks, int k0) {
#pragma unroll
    for (int i = 0; i < LA; ++i) {
      const int l2 = i * 512 + t;
      const int r = l2 >> 2, ck = l2 & 3;
      gload_lds16(A + (row0 + r) * (long)lda + k0 + ks * 32 + ck * 8,
                  Ab + (buf * 2 + ks) * BMT * 32 + (i * 512 + wv * 64) * 8);
    }
  };
  auto stageB = [&](int buf, int ks, int k0) {
#pragma unroll
    for (int i = 0; i < 2; ++i) {
      const int l2 = i * 512 + t;
      const int r = l2 >> 2, ck = l2 & 3;
      gload_lds16(B + (col0 + r) * (long)ldb + k0 + ks * 32 + ck * 8,
                  Bb + (buf * 2 + ks) * 256 * 32 + (i * 512 + wv * 64) * 8);
    }
  };

  bf16x8 bfr[4];
  auto loadB = [&](int buf, int ks) {
#pragma unroll
    for (int n = 0; n < 4; ++n)
      bfr[n] = *(const bf16x8*)(Bb + ((buf * 2 + ks) * 256 + wc * 64 + n * 16 + fr) * 32 + hi * 8);
  };
  auto phase = [&](int buf, int ks, int mlo) {
    bf16x8 afr[MF / 2];
#pragma unroll
    for (int m = 0; m < MF / 2; ++m)
      afr[m] = *(const bf16x8*)(Ab + ((buf * 2 + ks) * BMT + wr * (BMT / 2) + (mlo + m) * 16 + fr) * 32 + hi * 8);
    __builtin_amdgcn_s_setprio(1);
#pragma unroll
    for (int m = 0; m < MF / 2; ++m)
#pragma unroll
      for (int n = 0; n < 4; ++n)
        acc[mlo + m][n] = __builtin_amdgcn_mfma_f32_16x16x32_bf16(afr[m], bfr[n], acc[mlo + m][n], 0, 0, 0);
    __builtin_amdgcn_s_setprio(0);
  };

  // prologue: stage tile 0 fully, drain, barrier
  stageA(0, 0, 0); stageB(0, 0, 0); stageA(0, 1, 0); stageB(0, 1, 0);
  __builtin_amdgcn_sched_barrier(0);
  asm volatile("s_waitcnt vmcnt(0)" ::: "memory");
  __builtin_amdgcn_s_barrier();
  __builtin_amdgcn_sched_barrier(0);

  const int NT = K >> 6;
  for (int kt = 0; kt < NT; ++kt) {
    const int c = kt & 1;
    const int kn = (kt + 1 < NT) ? ((kt + 1) << 6) : 0;  // last iter: dummy re-stage
    stageA(c ^ 1, 0, kn); loadB(c, 0); phase(c, 0, 0);
    stageB(c ^ 1, 0, kn); phase(c, 0, MF / 2);
    __builtin_amdgcn_sched_barrier(0);
    if constexpr (LA == 2) asm volatile("s_waitcnt vmcnt(4)" ::: "memory");
    else                   asm volatile("s_waitcnt vmcnt(3)" ::: "memory");
    __builtin_amdgcn_s_barrier();
    __builtin_amdgcn_sched_barrier(0);
    stageA(c ^ 1, 1, kn); loadB(c, 1); phase(c, 1, 0);
    stageB(c ^ 1, 1, kn); phase(c, 1, MF / 2);
    __builtin_amdgcn_sched_barrier(0);
    if constexpr (LA == 2) asm volatile("s_waitcnt vmcnt(4)" ::: "memory");
    else                   asm volatile("s_waitcnt vmcnt(3)" ::: "memory");
    __builtin_amdgcn_s_barrier();
    __builtin_amdgcn_sched_barrier(0);
  }

  // epilogue
#pragma unroll
  for (int m = 0; m < MF; ++m)
#pragma unroll
    for (int n = 0; n < 4; ++n) {
      const long r0 = row0 + wr * (BMT / 2) + m * 16 + hi * 4;
      const long c = col0 + wc * 64 + n * 16 + fr;
      if (MODE == 0) {
        float* C = (float*)C0 + (long)blockIdx.z * sCz;
#pragma unroll
        for (int j = 0; j < 4; ++j) C[(r0 + j) * ldc + c] = acc[m][n][j];
      } else if (MODE == 1) {
        u16* C = (u16*)C0 + (long)blockIdx.z * sCz;
#pragma unroll
        for (int j = 0; j < 4; ++j) C[(r0 + j) * ldc + c] = f2bf(acc[m][n][j]);
      } else if (MODE == 2) {
        // m-dim = q within batch, n-dim = h; scramble: out2[2h + (q>>10)][q&1023]
        u16* C = (u16*)C0 + (long)blockIdx.z * sCz;
        const int q0 = (int)r0;
        const long dr = 2 * c + (q0 >> 10);
        bf16x4 pk;
#pragma unroll
        for (int j = 0; j < 4; ++j) pk[j] = (short)f2bf(acc[m][n][j]);
        *(bf16x4*)&C[dr * 1024 + (q0 & 1023)] = pk;
      } else {
        float* C = (float*)C0 + (long)blockIdx.z * sCz;
        const float bv = bias[c];
#pragma unroll
        for (int j = 0; j < 4; ++j) C[(r0 + j) * ldc + c] = acc[m][n][j] + bv;
      }
    }
}

// ---------------- launch ----------------
extern "C" void kernel_launch(void* const* d_in, const int* in_sizes, int n_in,
                              void* d_out, int out_size, void* d_ws, size_t ws_size,
                              hipStream_t stream) {
  const float* x      = (const float*)d_in[0];  // [4,2048,1024]
  const float* w_qkv  = (const float*)d_in[1];  // [3072,1024]
  const float* w_proj = (const float*)d_in[2];  // [1024,1024]
  const float* b_proj = (const float*)d_in[3];  // [1024]
  float* out = (float*)d_out;                   // [4,2048,1024]
  char* ws = (char*)d_ws;

  // ws layout (bytes)
  u16*   xb     = (u16*)(ws + 0);          // 16 MB
  u16*   wqkvb  = (u16*)(ws + 16777216);   //  6 MB
  u16*   wprojb = (u16*)(ws + 23068672);   //  2 MB
  u16*   qkvb   = (u16*)(ws + 25165824);   // 48 MB  [8192][3072]
  u16*   vT     = (u16*)(ws + 75497472);   // 16 MB  [4][1024][2048]
  u16*   out2   = (u16*)(ws + 92274688);   // 16 MB  [8192][1024] scrambled
  float* scores = (float*)(ws + 109051904);
  const bool full = ws_size >= 209715200ull;
  u16* probs = (u16*)(ws + (full ? 176160768 : 125829120));

  const int LDS256 = (4 * 256 * 32 + 4 * 256 * 32) * 2;  // 128 KB
  const int LDS128 = (4 * 128 * 32 + 4 * 256 * 32) * 2;  //  96 KB
  hipFuncSetAttribute((const void*)gemm8<1, 128>, hipFuncAttributeMaxDynamicSharedMemorySize, LDS128);
  hipFuncSetAttribute((const void*)gemm8<0, 256>, hipFuncAttributeMaxDynamicSharedMemorySize, LDS256);
  hipFuncSetAttribute((const void*)gemm8<2, 128>, hipFuncAttributeMaxDynamicSharedMemorySize, LDS128);
  hipFuncSetAttribute((const void*)gemm8<3, 128>, hipFuncAttributeMaxDynamicSharedMemorySize, LDS128);

  // 1) f32 -> bf16
  cvt_kernel<<<4096, 256, 0, stream>>>(x, xb, 1048576);
  cvt_kernel<<<1536, 256, 0, stream>>>(w_qkv, wqkvb, 393216);
  cvt_kernel<<<512, 256, 0, stream>>>(w_proj, wprojb, 131072);

  // 2) qkv = x @ w_qkv^T  (M=8192, N=3072, K=1024) -> bf16; 768 blocks = 3 full CU-waves
  gemm8<1, 128><<<dim3(12, 64, 1), 512, LDS128, stream>>>(xb, 1024, 0, wqkvb, 1024, 0,
                                                          qkvb, 3072, 0, nullptr, 1024);
  // 3) vT
  transpose_v<<<dim3(32, 16, 4), 256, 0, stream>>>(qkvb, vT);

  const long sQ = 2048L * 3072;
  if (full) {
    // 4) scores = q @ k^T (f32); 256 blocks = 1 CU-wave
    gemm8<0, 256><<<dim3(8, 8, 4), 512, LDS256, stream>>>(qkvb, 3072, sQ, qkvb + 1024, 3072, sQ,
                                                          scores, 2048, 2048L * 2048, nullptr, 1024);
    softmax_k<<<dim3(2048, 1, 4), 256, 0, stream>>>(scores, probs, 2048L * 2048, 2048L * 2048);
    // 5) out2 = probs @ vT^T (M=2048, N=1024, K=2048), scramble store; 256 blocks
    gemm8<2, 128><<<dim3(4, 16, 4), 512, LDS128, stream>>>(probs, 2048, 2048L * 2048, vT, 2048, 2048L * 1024,
                                                           out2, 1024, 2048L * 1024, nullptr, 2048);
  } else {
    for (int b = 0; b < 4; ++b) {
      const u16* qb = qkvb + (long)b * sQ;
      gemm8<0, 256><<<dim3(8, 8, 1), 512, LDS256, stream>>>(qb, 3072, 0, qb + 1024, 3072, 0,
                                                            scores, 2048, 0, nullptr, 1024);
      softmax_k<<<dim3(2048, 1, 1), 256, 0, stream>>>(scores, probs, 0, 0);
      gemm8<2, 128><<<dim3(4, 16, 1), 512, LDS128, stream>>>(probs, 2048, 0, vT + (long)b * 2048 * 1024, 2048, 0,
                                                             out2 + (long)b * 2048 * 1024, 1024, 0, nullptr, 2048);
    }
  }

  // 6) out = out2 @ w_proj^T + b_proj (M=8192, N=1024, K=1024) -> f32; 256 blocks
  gemm8<3, 128><<<dim3(4, 64, 1), 512, LDS128, stream>>>(out2, 1024, 0, wprojb, 1024, 0,
                                                         out, 1024, 0, b_proj, 1024);
}

// Round 4
// 295.289 us; speedup vs baseline: 1.1001x; 1.0133x over previous
//
#include <hip/hip_runtime.h>

// MultiHeadSelfAttention (faithful-bug version): qkv = x@Wqkv^T; attention over
// FULL 1024-dim "head"; scale 1/sqrt(64); probs@v; scramble reshape; proj + bias.
// B=4, S=2048, E=1024, H=1024, 3H=3072.
//
// gemm9: m201-style deep-pipelined NT GEMM (T1+T2+T3+T4+T5):
//  - 512 thr / 8 waves (2M x 4N), BN=256, BM in {128,256}, BK=64 as 2 K-halves
//  - LDS units [BM][32] / [256][32] (64B rows), slot^=(row&3) swizzle both sides
//  - stages for tile k+1 issued during tile k, one (A,B) unit-pair per half-phase
//  - per-phase s_waitcnt vmcnt(LA+2): issue->consume distance = 4 intervals
//  - split lgkmcnt(2)/(0) fences + setprio around 2 MFMA clusters per half

typedef float f32x4 __attribute__((ext_vector_type(4)));
typedef short bf16x8 __attribute__((ext_vector_type(8)));
typedef short bf16x4 __attribute__((ext_vector_type(4)));
typedef unsigned short u16;

__device__ inline u16 f2bf(float f) {  // round-to-nearest-even f32 -> bf16 bits
  union { float f; unsigned u; } x; x.f = f;
  unsigned r = x.u + 0x7fffu + ((x.u >> 16) & 1u);
  return (u16)(r >> 16);
}

__device__ inline void gload_lds16(const void* g, void* l) {
  __builtin_amdgcn_global_load_lds(
      (const __attribute__((address_space(1))) void*)g,
      (__attribute__((address_space(3))) void*)l, 16, 0, 0);
}

// ---------------- f32 -> bf16 conversion (memory-bound) ----------------
__global__ __launch_bounds__(256) void cvt_kernel(const float* __restrict__ in,
                                                  u16* __restrict__ out, int n8) {
  int i = blockIdx.x * 256 + threadIdx.x;
  if (i >= n8) return;
  f32x4 a = *(const f32x4*)&in[(long)i * 8];
  f32x4 b = *(const f32x4*)&in[(long)i * 8 + 4];
  bf16x8 o;
#pragma unroll
  for (int j = 0; j < 4; ++j) { o[j] = (short)f2bf(a[j]); o[4 + j] = (short)f2bf(b[j]); }
  *(bf16x8*)&out[(long)i * 8] = o;
}

// ---------------- V transpose: vT[b][h][k] = qkv[b][k][2048+h] ----------------
__global__ __launch_bounds__(256) void transpose_v(const u16* __restrict__ qkvb,
                                                   u16* __restrict__ vT) {
  __shared__ u16 tile[64][72];
  const int t = threadIdx.x;
  const long b = blockIdx.z;
  const int k0 = blockIdx.x * 64, h0 = blockIdx.y * 64;
  const u16* v = qkvb + b * 2048 * 3072 + 2048;
#pragma unroll
  for (int i = 0; i < 2; ++i) {
    int s = i * 256 + t; int r = s >> 3, c = (s & 7) * 8;
    bf16x8 val = *(const bf16x8*)&v[(long)(k0 + r) * 3072 + h0 + c];
    *(bf16x8*)&tile[r][c] = val;
  }
  __syncthreads();
  u16* o = vT + b * 1024 * 2048;
#pragma unroll
  for (int i = 0; i < 2; ++i) {
    int s = i * 256 + t; int r = s >> 3, c = (s & 7) * 8;
    bf16x8 val;
#pragma unroll
    for (int j = 0; j < 8; ++j) val[j] = tile[c + j][r];
    *(bf16x8*)&o[(long)(h0 + r) * 2048 + k0 + c] = val;
  }
}

// ---------------- row softmax: probs = softmax(scores * 0.125), bf16 out ------
__global__ __launch_bounds__(256) void softmax_k(const float* __restrict__ S,
                                                 u16* __restrict__ P,
                                                 long sS, long sP) {
  const int t = threadIdx.x;
  const float* row = S + (long)blockIdx.z * sS + (long)blockIdx.x * 2048;
  u16* prow = P + (long)blockIdx.z * sP + (long)blockIdx.x * 2048;
  f32x4 v0 = *(const f32x4*)&row[t * 8];
  f32x4 v1 = *(const f32x4*)&row[t * 8 + 4];
  float m = v0[0];
#pragma unroll
  for (int j = 1; j < 4; ++j) m = fmaxf(m, v0[j]);
#pragma unroll
  for (int j = 0; j < 4; ++j) m = fmaxf(m, v1[j]);
#pragma unroll
  for (int o = 32; o; o >>= 1) m = fmaxf(m, __shfl_xor(m, o));
  __shared__ float red[8];
  if ((t & 63) == 0) red[t >> 6] = m;
  __syncthreads();
  m = fmaxf(fmaxf(red[0], red[1]), fmaxf(red[2], red[3]));
  const float C = 0.18033688011112042f;  // 0.125 * log2(e)
  float e[8], s = 0.f;
#pragma unroll
  for (int j = 0; j < 4; ++j) { e[j] = exp2f((v0[j] - m) * C); s += e[j]; }
#pragma unroll
  for (int j = 0; j < 4; ++j) { e[4 + j] = exp2f((v1[j] - m) * C); s += e[4 + j]; }
#pragma unroll
  for (int o = 32; o; o >>= 1) s += __shfl_xor(s, o);
  if ((t & 63) == 0) red[4 + (t >> 6)] = s;
  __syncthreads();
  float inv = 1.f / (red[4] + red[5] + red[6] + red[7]);
  bf16x8 ov;
#pragma unroll
  for (int j = 0; j < 8; ++j) ov[j] = (short)f2bf(e[j] * inv);
  *(bf16x8*)&prow[t * 8] = ov;
}

// ======== gemm9: deep-pipelined NT GEMM: C[m][n] = sum_k A[m][k]*B[n][k] ======
// MODE 0: f32 store | 1: bf16 store | 2: bf16 scramble store (PV) | 3: f32+bias
template <int MODE, int BM>
__global__ __launch_bounds__(512, 2) void gemm9(const u16* __restrict__ A0, int lda, long sAz,
                                                const u16* __restrict__ B0, int ldb, long sBz,
                                                void* __restrict__ C0, int ldc, long sCz,
                                                const float* __restrict__ bias, int K) {
  constexpr int MR = BM / 32;   // A frags per wave (8 or 4)
  constexpr int LA = BM / 128;  // gloads per thread per A-unit (2 or 1)
  extern __shared__ __align__(16) u16 smem[];
  u16* Ab = smem;                  // [2buf][2ks][BM][32]
  u16* Bb = smem + 4 * BM * 32;    // [2buf][2ks][256][32]
  const int t = threadIdx.x, lane = t & 63, wv = t >> 6;
  const int wr = wv >> 2, wc = wv & 3;
  const int fr = lane & 15, hi = lane >> 4;

  // bijective XCD-chunk swizzle over the full grid (all our grids are %8==0)
  const int gx = gridDim.x, gy = gridDim.y;
  long L = ((long)blockIdx.z * gy + blockIdx.y) * gx + blockIdx.x;
  const long NB = (long)gx * gy * gridDim.z;
  if ((NB & 7) == 0) L = (L & 7) * (NB >> 3) + (L >> 3);
  const int bx = (int)(L % gx);
  const int by = (int)((L / gx) % gy);
  const int bz = (int)(L / ((long)gx * gy));

  const long row0 = (long)by * BM, col0 = (long)bx * 256;
  const u16* A = A0 + (long)bz * sAz;
  const u16* B = B0 + (long)bz * sBz;

  f32x4 acc[MR][4];
#pragma unroll
  for (int m = 0; m < MR; ++m)
#pragma unroll
    for (int n = 0; n < 4; ++n) acc[m][n] = (f32x4){0.f, 0.f, 0.f, 0.f};

  // stage one (A,B) unit pair for K-half ks of tile at k-offset k0 into buf
  auto stA = [&](int buf, int ks, int k0) {
#pragma unroll
    for (int i = 0; i < LA; ++i) {
      const int l = i * 512 + t;
      const int r = l >> 2, sl = (l & 3) ^ (r & 3);  // slot swizzle (source side)
      gload_lds16(A + (row0 + r) * (long)lda + k0 + ks * 32 + sl * 8,
                  Ab + (buf * 2 + ks) * BM * 32 + (i * 512 + wv * 64) * 8);
    }
  };
  auto stB = [&](int buf, int ks, int k0) {
#pragma unroll
    for (int i = 0; i < 2; ++i) {
      const int l = i * 512 + t;
      const int r = l >> 2, sl = (l & 3) ^ (r & 3);
      gload_lds16(B + (col0 + r) * (long)ldb + k0 + ks * 32 + sl * 8,
                  Bb + (buf * 2 + ks) * 256 * 32 + (i * 512 + wv * 64) * 8);
    }
  };
  // swizzled fragment addresses (read side; row&3 == fr&3 since bases %16==0)
  auto aAddr = [&](int buf, int ks, int m) -> const u16* {
    const int r = wr * (BM / 2) + m * 16 + fr;
    return Ab + ((buf * 2 + ks) * BM + r) * 32 + (hi ^ (fr & 3)) * 8;
  };
  auto bAddr = [&](int buf, int ks, int n) -> const u16* {
    const int r = wc * 64 + n * 16 + fr;
    return Bb + ((buf * 2 + ks) * 256 + r) * 32 + (hi ^ (fr & 3)) * 8;
  };

  // prologue: stage both K-halves of tile 0
  stA(0, 0, 0); stB(0, 0, 0);
  stA(0, 1, 0); stB(0, 1, 0);

  const int NT = K >> 6;
  for (int kt = 0; kt < NT; ++kt) {
    const int buf = kt & 1;
    const int kn = (kt + 1) << 6;
    const bool pf = (kt + 1 < NT);
#pragma unroll
    for (int ks = 0; ks < 2; ++ks) {
      // entry: allow the most recent unit-pair to stay in flight
      if constexpr (LA == 2) asm volatile("s_waitcnt vmcnt(4)" ::: "memory");
      else                   asm volatile("s_waitcnt vmcnt(3)" ::: "memory");
      __builtin_amdgcn_s_barrier();
      __builtin_amdgcn_sched_barrier(0);
      bf16x8 afr[MR], b01[2], b23[2];
#pragma unroll
      for (int m = 0; m < MR; ++m) afr[m] = *(const bf16x8*)aAddr(buf, ks, m);
#pragma unroll
      for (int n = 0; n < 2; ++n) b01[n] = *(const bf16x8*)bAddr(buf, ks, n);
#pragma unroll
      for (int n = 0; n < 2; ++n) b23[n] = *(const bf16x8*)bAddr(buf, ks, 2 + n);
      if (pf) { stA(buf ^ 1, ks, kn); stB(buf ^ 1, ks, kn); }
      asm volatile("s_waitcnt lgkmcnt(2)" ::: "memory");  // afr + b01 ready
      __builtin_amdgcn_sched_barrier(0);
      __builtin_amdgcn_s_setprio(1);
#pragma unroll
      for (int m = 0; m < MR; ++m) {
        acc[m][0] = __builtin_amdgcn_mfma_f32_16x16x32_bf16(afr[m], b01[0], acc[m][0], 0, 0, 0);
        acc[m][1] = __builtin_amdgcn_mfma_f32_16x16x32_bf16(afr[m], b01[1], acc[m][1], 0, 0, 0);
      }
      __builtin_amdgcn_s_setprio(0);
      asm volatile("s_waitcnt lgkmcnt(0)" ::: "memory");  // b23 ready
      __builtin_amdgcn_sched_barrier(0);
      __builtin_amdgcn_s_setprio(1);
#pragma unroll
      for (int m = 0; m < MR; ++m) {
        acc[m][2] = __builtin_amdgcn_mfma_f32_16x16x32_bf16(afr[m], b23[0], acc[m][2], 0, 0, 0);
        acc[m][3] = __builtin_amdgcn_mfma_f32_16x16x32_bf16(afr[m], b23[1], acc[m][3], 0, 0, 0);
      }
      __builtin_amdgcn_s_setprio(0);
    }
  }

  // epilogue
#pragma unroll
  for (int m = 0; m < MR; ++m)
#pragma unroll
    for (int n = 0; n < 4; ++n) {
      const long r0 = row0 + wr * (BM / 2) + m * 16 + hi * 4;
      const long c = col0 + wc * 64 + n * 16 + fr;
      if (MODE == 0) {
        float* C = (float*)C0 + (long)bz * sCz;
#pragma unroll
        for (int j = 0; j < 4; ++j) C[(r0 + j) * ldc + c] = acc[m][n][j];
      } else if (MODE == 1) {
        u16* C = (u16*)C0 + (long)bz * sCz;
#pragma unroll
        for (int j = 0; j < 4; ++j) C[(r0 + j) * ldc + c] = f2bf(acc[m][n][j]);
      } else if (MODE == 2) {
        // m-dim = q within batch, n-dim = h; scramble: out2[2h + (q>>10)][q&1023]
        u16* C = (u16*)C0 + (long)bz * sCz;
        const int q0 = (int)r0;
        const long dr = 2 * c + (q0 >> 10);
        bf16x4 pk;
#pragma unroll
        for (int j = 0; j < 4; ++j) pk[j] = (short)f2bf(acc[m][n][j]);
        *(bf16x4*)&C[dr * 1024 + (q0 & 1023)] = pk;
      } else {
        float* C = (float*)C0 + (long)bz * sCz;
        const float bv = bias[c];
#pragma unroll
        for (int j = 0; j < 4; ++j) C[(r0 + j) * ldc + c] = acc[m][n][j] + bv;
      }
    }
}

// ---------------- launch ----------------
extern "C" void kernel_launch(void* const* d_in, const int* in_sizes, int n_in,
                              void* d_out, int out_size, void* d_ws, size_t ws_size,
                              hipStream_t stream) {
  const float* x      = (const float*)d_in[0];  // [4,2048,1024]
  const float* w_qkv  = (const float*)d_in[1];  // [3072,1024]
  const float* w_proj = (const float*)d_in[2];  // [1024,1024]
  const float* b_proj = (const float*)d_in[3];  // [1024]
  float* out = (float*)d_out;                   // [4,2048,1024]
  char* ws = (char*)d_ws;

  // ws layout (bytes)
  u16*   xb     = (u16*)(ws + 0);          // 16 MB
  u16*   wqkvb  = (u16*)(ws + 16777216);   //  6 MB
  u16*   wprojb = (u16*)(ws + 23068672);   //  2 MB
  u16*   qkvb   = (u16*)(ws + 25165824);   // 48 MB  [8192][3072]
  u16*   vT     = (u16*)(ws + 75497472);   // 16 MB  [4][1024][2048]
  u16*   out2   = (u16*)(ws + 92274688);   // 16 MB  [8192][1024] scrambled
  float* scores = (float*)(ws + 109051904);
  const bool full = ws_size >= 209715200ull;
  u16* probs = (u16*)(ws + (full ? 176160768 : 125829120));

  const int LDS128 = (4 * 128 * 32 + 4 * 256 * 32) * 2;  //  96 KB
  const int LDS256 = (4 * 256 * 32 + 4 * 256 * 32) * 2;  // 128 KB
  hipFuncSetAttribute((const void*)gemm9<1, 128>, hipFuncAttributeMaxDynamicSharedMemorySize, LDS128);
  hipFuncSetAttribute((const void*)gemm9<0, 256>, hipFuncAttributeMaxDynamicSharedMemorySize, LDS256);
  hipFuncSetAttribute((const void*)gemm9<2, 128>, hipFuncAttributeMaxDynamicSharedMemorySize, LDS128);
  hipFuncSetAttribute((const void*)gemm9<3, 128>, hipFuncAttributeMaxDynamicSharedMemorySize, LDS128);

  // 1) f32 -> bf16
  cvt_kernel<<<4096, 256, 0, stream>>>(x, xb, 1048576);
  cvt_kernel<<<1536, 256, 0, stream>>>(w_qkv, wqkvb, 393216);
  cvt_kernel<<<512, 256, 0, stream>>>(w_proj, wprojb, 131072);

  // 2) qkv = x @ w_qkv^T  (M=8192, N=3072, K=1024) -> bf16; 768 blocks
  gemm9<1, 128><<<dim3(12, 64, 1), 512, LDS128, stream>>>(xb, 1024, 0, wqkvb, 1024, 0,
                                                          qkvb, 3072, 0, nullptr, 1024);
  // 3) vT
  transpose_v<<<dim3(32, 16, 4), 256, 0, stream>>>(qkvb, vT);

  const long sQ = 2048L * 3072;
  if (full) {
    // 4) scores = q @ k^T (f32); 256 blocks
    gemm9<0, 256><<<dim3(8, 8, 4), 512, LDS256, stream>>>(qkvb, 3072, sQ, qkvb + 1024, 3072, sQ,
                                                          scores, 2048, 2048L * 2048, nullptr, 1024);
    softmax_k<<<dim3(2048, 1, 4), 256, 0, stream>>>(scores, probs, 2048L * 2048, 2048L * 2048);
    // 5) out2 = probs @ vT^T (M=2048, N=1024, K=2048), scramble store; 256 blocks
    gemm9<2, 128><<<dim3(4, 16, 4), 512, LDS128, stream>>>(probs, 2048, 2048L * 2048, vT, 2048, 2048L * 1024,
                                                           out2, 1024, 2048L * 1024, nullptr, 2048);
  } else {
    for (int b = 0; b < 4; ++b) {
      const u16* qb = qkvb + (long)b * sQ;
      gemm9<0, 256><<<dim3(8, 8, 1), 512, LDS256, stream>>>(qb, 3072, 0, qb + 1024, 3072, 0,
                                                            scores, 2048, 0, nullptr, 1024);
      softmax_k<<<dim3(2048, 1, 1), 256, 0, stream>>>(scores, probs, 0, 0);
      gemm9<2, 128><<<dim3(4, 16, 1), 512, LDS128, stream>>>(probs, 2048, 0, vT + (long)b * 2048 * 1024, 2048, 0,
                                                             out2 + (long)b * 2048 * 1024, 1024, 0, nullptr, 2048);
    }
  }

  // 6) out = out2 @ w_proj^T + b_proj (M=8192, N=1024, K=1024) -> f32; 256 blocks
  gemm9<3, 128><<<dim3(4, 64, 1), 512, LDS128, stream>>>(out2, 1024, 0, wprojb, 1024, 0,
                                                         out, 1024, 0, b_proj, 1024);
}